// Round 4
// baseline (195.989 us; speedup 1.0000x reference)
//
#include <hip/hip_runtime.h>
#include <hip/hip_bf16.h>

// Problem constants (fixed by the reference setup)
#define BGR  128          // graphs
#define NPG  111          // nodes per graph
#define HDIM 32           // hidden
#define EPG  (NPG*(NPG-1))// 12210 directed edges per graph
#define NTOT (BGR*NPG)    // 14208 nodes
#define PADW 112          // global row length for eatt rows ([d][s])
#define PADT 113          // eatt LDS-internal pad (bank step 17, conflict-free)
#define TSTR 116          // hs_t row stride: b128 @ stride 116 tiles all 32 banks
#define DPB  14           // dsts per gat block (8 blocks per graph)

// ---------------------------------------------------------------------------
// Kernel 1: per-layer edge-attention scalar, transposed to [g][d][s] layout.
// eatt[s->d] = ea.x*c0 + ea.y*c1 with (c0,c1) = We @ ae.
// Diagonal (self-loop, fill='mean') = rowsum/110 (linear in ea).
// grid = 3*BGR blocks of 256.
__global__ void eatt_kernel(const float* __restrict__ ea,
                            const float* __restrict__ We0, const float* __restrict__ ae0,
                            const float* __restrict__ We1, const float* __restrict__ ae1,
                            const float* __restrict__ We2, const float* __restrict__ ae2,
                            float* __restrict__ eatt) {
    int l = blockIdx.x / BGR;
    int g = blockIdx.x % BGR;
    const float* We = (l == 0) ? We0 : ((l == 1) ? We1 : We2);
    const float* ae = (l == 0) ? ae0 : ((l == 1) ? ae1 : ae2);

    __shared__ float tile[NPG * PADT];
    __shared__ float cvec[2];
    int t = threadIdx.x;

    if (t < 64) {
        int r = t >> 5, k = t & 31;
        float p = We[r * 32 + k] * ae[k];
        for (int off = 1; off < 32; off <<= 1) p += __shfl_xor(p, off);
        if (k == 0) cvec[r] = p;
    }
    __syncthreads();
    float c0 = cvec[0], c1 = cvec[1];

    const float* eg = ea + (size_t)g * EPG * 2;
    for (int e = t; e < EPG; e += 256) {
        float2 v = ((const float2*)eg)[e];
        int s = e / 110;
        int j = e - s * 110;
        int d = j + (j >= s ? 1 : 0);
        tile[d * PADT + s] = v.x * c0 + v.y * c1;
    }
    __syncthreads();

    int wave = t >> 6, lane = t & 63;
    for (int d = wave; d < NPG; d += 4) {
        float a = (lane != d) ? tile[d * PADT + lane] : 0.f;
        int s2 = lane + 64;
        float b = (s2 < NPG && s2 != d) ? tile[d * PADT + s2] : 0.f;
        float p = a + b;
        for (int off = 1; off < 64; off <<= 1) p += __shfl_xor(p, off);
        if (lane == 0) tile[d * PADT + d] = p * (1.f / 110.f);
    }
    __syncthreads();

    float* out = eatt + (size_t)(l * BGR + g) * NPG * PADW;
    for (int i = t; i < NPG * PADW; i += 256) {
        int d = i / PADW, s = i - d * PADW;
        out[i] = tile[d * PADT + s];   // col 111 is never consumed downstream
    }
}

// ---------------------------------------------------------------------------
// Kernel 2: fused proj + GAT layer.
// grid = BGR*8 blocks of 256; block = (graph g, 14-dst slice). Each block
// recomputes the full 111x32 projection of its graph (W in registers),
// writes h transposed into hs_t[c][TSTR] for vectorized aggregation.
__global__ __launch_bounds__(256, 4) void
gat_fused(const float* __restrict__ xin,   // din1: [NTOT]; else [NTOT*32]
          int din1, int do_relu,
          const float* __restrict__ W,     // [din][32]
          const float* __restrict__ as_w, const float* __restrict__ ad_w,
          const float* __restrict__ eatt_l,// [BGR][NPG][PADW]
          const float* __restrict__ bias,
          float* __restrict__ h_out) {
    int g = blockIdx.x >> 3;
    int part = blockIdx.x & 7;
    int t = threadIdx.x;
    int wave = t >> 6, lane = t & 63;
    int c = lane & 31;
    int il = t >> 5;                       // 0..7 node slot

    __shared__ float hprev[NPG * 32];      // din1: only [0..110] used (=x)
    __shared__ float hs_t[32 * TSTR];      // transposed h
    __shared__ float ass[112];
    __shared__ float ads[112];
    __shared__ float coef[4][4][PADW];     // per-wave softmax coefs

    // per-thread weight column + attention weights (broadcast global loads)
    float wcol[32];
    float aswv = as_w[c];
    float adwv = ad_w[c];
    float bv   = bias[c];
    if (din1) {
        wcol[0] = W[c];
    } else {
        #pragma unroll
        for (int k = 0; k < 32; k++) wcol[k] = W[k * 32 + c];
    }

    // ---- stage input features ----
    if (din1) {
        if (t < NPG) hprev[t] = xin[g * NPG + t];
    } else {
        const float4* src = (const float4*)(xin + (size_t)g * NPG * 32);
        for (int i = t; i < NPG * 8; i += 256) ((float4*)hprev)[i] = src[i];
    }
    if (t < 32) hs_t[t * TSTR + 111] = 0.f;   // zero pad column (s=111)
    __syncthreads();

    // ---- proj: h[s][c] (+ ass/ads dots), nodes s = pass*8 + il ----
    for (int pass = 0; pass < 14; pass++) {
        int s = pass * 8 + il;
        bool vs = (s < NPG);
        float hv = 0.f;
        if (vs) {
            if (din1) {
                hv = hprev[s] * wcol[0];
            } else {
                #pragma unroll
                for (int k = 0; k < 32; k++) {
                    float xv = hprev[s * 32 + k];
                    if (do_relu) xv = fmaxf(xv, 0.f);
                    hv += xv * wcol[k];
                }
            }
            hs_t[c * TSTR + s] = hv;
        }
        float ps = hv * aswv, pd = hv * adwv;
        #pragma unroll
        for (int off = 1; off < 32; off <<= 1) {
            ps += __shfl_xor(ps, off);
            pd += __shfl_xor(pd, off);
        }
        if (vs && c == 0) { ass[s] = ps; ads[s] = pd; }
    }
    __syncthreads();   // hs_t / ass / ads visible block-wide

    // ---- scores + softmax: 4 dsts per wave, eatt read straight from global ----
    bool actp[4];
    #pragma unroll
    for (int p = 0; p < 4; p++) {
        int dl = wave * 4 + p;
        int d = part * DPB + dl;
        bool act = (dl < DPB) && (d < NPG);
        actp[p] = act;
        float s1 = -1e30f, s2 = -1e30f;
        if (act) {
            const float* er = eatt_l + ((size_t)g * NPG + d) * PADW;
            float add = ads[d];
            float a1 = ass[lane] + add + er[lane];
            s1 = (a1 > 0.f) ? a1 : 0.2f * a1;
            int sB = lane + 64;
            if (sB < NPG) {
                float a2 = ass[sB] + add + er[sB];
                s2 = (a2 > 0.f) ? a2 : 0.2f * a2;
            }
        }
        float m = fmaxf(s1, s2);
        for (int off = 1; off < 64; off <<= 1) m = fmaxf(m, __shfl_xor(m, off));
        float e1 = (s1 > -1e29f) ? __expf(s1 - m) : 0.f;
        float e2 = (s2 > -1e29f) ? __expf(s2 - m) : 0.f;
        float sum = e1 + e2;
        for (int off = 1; off < 64; off <<= 1) sum += __shfl_xor(sum, off);
        float inv = (sum > 0.f) ? (1.f / sum) : 0.f;
        coef[wave][p][lane] = e1 * inv;
        if (lane + 64 < PADW)
            coef[wave][p][lane + 64] = (lane + 64 < NPG) ? e2 * inv : 0.f;
    }
    // per-wave coef: same-wave LDS write->read is ordered, no barrier needed

    // ---- aggregation: float4 over s; 1 hs_t b128 + 4 coef b128 per 4 srcs ----
    int sbase = (lane >> 5) * 56;          // half 0: s 0..55, half 1: 56..111
    float acc0 = 0.f, acc1 = 0.f, acc2 = 0.f, acc3 = 0.f;
    #pragma unroll
    for (int j4 = 0; j4 < 56; j4 += 4) {
        int s4 = sbase + j4;
        float4 hval = *(const float4*)&hs_t[c * TSTR + s4];
        float4 q0 = *(const float4*)&coef[wave][0][s4];
        float4 q1 = *(const float4*)&coef[wave][1][s4];
        float4 q2 = *(const float4*)&coef[wave][2][s4];
        float4 q3 = *(const float4*)&coef[wave][3][s4];
        acc0 += q0.x * hval.x + q0.y * hval.y + q0.z * hval.z + q0.w * hval.w;
        acc1 += q1.x * hval.x + q1.y * hval.y + q1.z * hval.z + q1.w * hval.w;
        acc2 += q2.x * hval.x + q2.y * hval.y + q2.z * hval.z + q2.w * hval.w;
        acc3 += q3.x * hval.x + q3.y * hval.y + q3.z * hval.z + q3.w * hval.w;
    }
    acc0 += __shfl_xor(acc0, 32);
    acc1 += __shfl_xor(acc1, 32);
    acc2 += __shfl_xor(acc2, 32);
    acc3 += __shfl_xor(acc3, 32);
    if (lane < 32) {
        size_t dbase = (size_t)g * NPG + part * DPB + wave * 4;
        if (actp[0]) h_out[(dbase + 0) * 32 + lane] = acc0 + bv;
        if (actp[1]) h_out[(dbase + 1) * 32 + lane] = acc1 + bv;
        if (actp[2]) h_out[(dbase + 2) * 32 + lane] = acc2 + bv;
        if (actp[3]) h_out[(dbase + 3) * 32 + lane] = acc3 + bv;
    }
}

// ---------------------------------------------------------------------------
// Kernel 3: global_add_pool + final linear + relu. grid = BGR blocks of 256.
__global__ void pool_kernel(const float* __restrict__ h2,
                            const float* __restrict__ linW,
                            const float* __restrict__ linb,
                            float* __restrict__ out) {
    int g = blockIdx.x;
    int t = threadIdx.x;
    int c = t & 31, r = t >> 5;
    const float* hg = h2 + (size_t)g * NPG * 32;
    float acc = 0.f;
    for (int i = r; i < NPG; i += 8) acc += hg[i * 32 + c];
    __shared__ float red[8][33];
    red[r][c] = acc;
    __syncthreads();
    if (t < 32) {
        float p = 0.f;
        #pragma unroll
        for (int rr = 0; rr < 8; rr++) p += red[rr][t];
        p *= linW[t];
        for (int off = 1; off < 32; off <<= 1) p += __shfl_xor(p, off);
        if (t == 0) out[g] = fmaxf(p + linb[0], 0.f);
    }
}

// ---------------------------------------------------------------------------
extern "C" void kernel_launch(void* const* d_in, const int* in_sizes, int n_in,
                              void* d_out, int out_size, void* d_ws, size_t ws_size,
                              hipStream_t stream) {
    // input order: x, edge_index, edge_attr, {W,as,ad,We,ae,b} x3, lin_W, lin_b
    const float* x    = (const float*)d_in[0];
    const float* ea   = (const float*)d_in[2];
    const float* W[3]  = {(const float*)d_in[3],  (const float*)d_in[9],  (const float*)d_in[15]};
    const float* as_[3]= {(const float*)d_in[4],  (const float*)d_in[10], (const float*)d_in[16]};
    const float* ad_[3]= {(const float*)d_in[5],  (const float*)d_in[11], (const float*)d_in[17]};
    const float* We[3] = {(const float*)d_in[6],  (const float*)d_in[12], (const float*)d_in[18]};
    const float* ae[3] = {(const float*)d_in[7],  (const float*)d_in[13], (const float*)d_in[19]};
    const float* b[3]  = {(const float*)d_in[8],  (const float*)d_in[14], (const float*)d_in[20]};
    const float* linW  = (const float*)d_in[21];
    const float* linb  = (const float*)d_in[22];
    float* out = (float*)d_out;

    float* ws   = (float*)d_ws;
    float* eatt = ws;                                     // 3*BGR*NPG*PADW
    float* h0   = eatt + (size_t)3 * BGR * NPG * PADW;    // NTOT*32
    float* h1   = h0   + (size_t)NTOT * 32;               // NTOT*32

    eatt_kernel<<<3 * BGR, 256, 0, stream>>>(ea, We[0], ae[0], We[1], ae[1],
                                             We[2], ae[2], eatt);

    gat_fused<<<BGR * 8, 256, 0, stream>>>(x, 1, 0, W[0], as_[0], ad_[0],
                                           eatt + (size_t)0 * BGR * NPG * PADW,
                                           b[0], h0);
    gat_fused<<<BGR * 8, 256, 0, stream>>>(h0, 0, 0, W[1], as_[1], ad_[1],
                                           eatt + (size_t)1 * BGR * NPG * PADW,
                                           b[1], h1);
    gat_fused<<<BGR * 8, 256, 0, stream>>>(h1, 0, 1, W[2], as_[2], ad_[2],
                                           eatt + (size_t)2 * BGR * NPG * PADW,
                                           b[2], h0);

    pool_kernel<<<BGR, 256, 0, stream>>>(h0, linW, linb, out);
}

// Round 5
// 178.609 us; speedup vs baseline: 1.0973x; 1.0973x over previous
//
#include <hip/hip_runtime.h>
#include <hip/hip_bf16.h>

// Problem constants (fixed by the reference setup)
#define BGR  128          // graphs
#define NPG  111          // nodes per graph
#define HDIM 32           // hidden
#define EPG  (NPG*(NPG-1))// 12210 directed edges per graph
#define NTOT (BGR*NPG)    // 14208 nodes
#define PADW 112          // global row length for eatt rows ([d][s])
#define PADT 113          // eatt LDS-internal pad (bank step 17, conflict-free)
#define TSTR 116          // hs_t row stride (4-word aligned; ~free conflicts)
#define DPB  14           // dsts per gat block (8 blocks per graph)
#define SCRF (NPG*36)     // scratch floats: hprev[111][36], later coef[16][112]

// ---------------------------------------------------------------------------
// Kernel 1: per-layer edge-attention scalar, transposed to [g][d][s] layout.
// eatt[s->d] = ea.x*c0 + ea.y*c1 with (c0,c1) = We @ ae.
// Diagonal (self-loop, fill='mean') = rowsum/110 (linear in ea).
// grid = 3*BGR blocks of 256.
__global__ void eatt_kernel(const float* __restrict__ ea,
                            const float* __restrict__ We0, const float* __restrict__ ae0,
                            const float* __restrict__ We1, const float* __restrict__ ae1,
                            const float* __restrict__ We2, const float* __restrict__ ae2,
                            float* __restrict__ eatt) {
    int l = blockIdx.x / BGR;
    int g = blockIdx.x % BGR;
    const float* We = (l == 0) ? We0 : ((l == 1) ? We1 : We2);
    const float* ae = (l == 0) ? ae0 : ((l == 1) ? ae1 : ae2);

    __shared__ float tile[NPG * PADT];
    __shared__ float cvec[2];
    int t = threadIdx.x;

    if (t < NPG) tile[t * PADT + t] = 0.f;   // diagonal = 0 so row-sum works
    if (t < 64) {
        int r = t >> 5, k = t & 31;
        float p = We[r * 32 + k] * ae[k];
        for (int off = 1; off < 32; off <<= 1) p += __shfl_xor(p, off);
        if (k == 0) cvec[r] = p;
    }
    __syncthreads();
    float c0 = cvec[0], c1 = cvec[1];

    const float* eg = ea + (size_t)g * EPG * 2;
    for (int e = t; e < EPG; e += 256) {
        float2 v = ((const float2*)eg)[e];
        int s = e / 110;
        int j = e - s * 110;
        int d = j + (j >= s ? 1 : 0);
        tile[d * PADT + s] = v.x * c0 + v.y * c1;  // never writes the diagonal
    }
    __syncthreads();

    // diagonal = mean of incoming: thread-per-row LDS sweep (stride 113 ->
    // conflict-free across lanes), zero shuffles.
    if (t < NPG) {
        float sum = 0.f;
        #pragma unroll 8
        for (int s = 0; s < NPG; s++) sum += tile[t * PADT + s];
        tile[t * PADT + t] = sum * (1.f / 110.f);
    }
    __syncthreads();

    float* out = eatt + (size_t)(l * BGR + g) * NPG * PADW;
    for (int i = t; i < NPG * PADW; i += 256) {
        int d = i / PADW, s = i - d * PADW;
        out[i] = tile[d * PADT + s];   // col 111 is garbage; never read
    }
}

// ---------------------------------------------------------------------------
// Kernel 2: fused proj + GAT layer, reduction-free softmax.
//  - proj -> hs_t (transposed h), zero shuffles
//  - as/ad: thread-per-node conflict-free column dots, zero shuffles
//  - scores: elementwise exp(leaky(...)), no max-sub, no sum (denominator
//    recovered inside aggregation from the broadcast coef reads)
//  - agg: float4 LDS, 4 dsts/wave, 8 shuffles total per wave
// grid = BGR*8 blocks of 256.
__global__ __launch_bounds__(256) void
gat_fused(const float* __restrict__ xin,   // din1: [NTOT]; else [NTOT*32]
          int din1, int do_relu,
          const float* __restrict__ W,     // [din][32]
          const float* __restrict__ as_w, const float* __restrict__ ad_w,
          const float* __restrict__ eatt_l,// [BGR][NPG][PADW]
          const float* __restrict__ bias,
          float* __restrict__ h_out) {
    int g = blockIdx.x >> 3;
    int part = blockIdx.x & 7;
    int t = threadIdx.x;
    int wave = t >> 6, lane = t & 63;
    int c = lane & 31;

    __shared__ float scratch[SCRF];       // hprev[111][36] then coef[16][112]
    __shared__ float hs_t[32 * TSTR];     // transposed h, col 111 zeroed
    __shared__ float Ws[32 * 32];
    __shared__ float ass[112], ads[112];
    __shared__ float asw[32], adw[32];

    // ---- stage ----
    if (din1) {
        if (t < NPG) scratch[t] = xin[g * NPG + t];
        if (t < 32) Ws[t] = W[t];
    } else {
        const float4* src = (const float4*)(xin + (size_t)g * NPG * 32);
        for (int i = t; i < NPG * 8; i += 256) {
            float4 v = src[i];
            *(float4*)&scratch[(i >> 3) * 36 + (i & 7) * 4] = v;
        }
        for (int i = t; i < 1024; i += 256) Ws[i] = W[i];
    }
    if (t < 32) { asw[t] = as_w[t]; adw[t] = ad_w[t]; hs_t[t * TSTR + 111] = 0.f; }
    __syncthreads();

    // ---- proj: thread=(node slot, channel); broadcast input reads ----
    int il = t >> 5;                      // 0..7
    for (int pass = 0; pass < 14; pass++) {
        int s = pass * 8 + il;
        if (s < NPG) {
            float hv;
            if (din1) {
                hv = scratch[s] * Ws[c];
            } else {
                float acc = 0.f;
                const float4* row = (const float4*)&scratch[s * 36];
                #pragma unroll
                for (int k4 = 0; k4 < 8; k4++) {
                    float4 xv = row[k4];
                    if (do_relu) {
                        xv.x = fmaxf(xv.x, 0.f); xv.y = fmaxf(xv.y, 0.f);
                        xv.z = fmaxf(xv.z, 0.f); xv.w = fmaxf(xv.w, 0.f);
                    }
                    acc += xv.x * Ws[(k4 * 4 + 0) * 32 + c]
                         + xv.y * Ws[(k4 * 4 + 1) * 32 + c]
                         + xv.z * Ws[(k4 * 4 + 2) * 32 + c]
                         + xv.w * Ws[(k4 * 4 + 3) * 32 + c];
                }
                hv = acc;
            }
            hs_t[c * TSTR + s] = hv;
        }
    }
    __syncthreads();   // hs_t complete (hprev now dead)

    // ---- as/ad: thread-per-node column dots (lane-stride-1: conflict-free) ----
    if (t < NPG) {
        float sa = 0.f, sd = 0.f;
        #pragma unroll 8
        for (int cc = 0; cc < 32; cc++) {
            float hv = hs_t[cc * TSTR + t];
            sa += hv * asw[cc];
            sd += hv * adw[cc];
        }
        ass[t] = sa; ads[t] = sd;
    }
    __syncthreads();

    // ---- scores: pure elementwise, coef overlays scratch ----
    float* coef = scratch;
    bool actp[4];
    const float* erp[4];
    #pragma unroll
    for (int p = 0; p < 4; p++) {
        int dl = wave * 4 + p;
        int d = part * DPB + dl;
        actp[p] = (dl < DPB) && (d < NPG);
        erp[p] = eatt_l + ((size_t)g * NPG + d) * PADW;
    }
    // issue all global loads first
    float erA[4], erB[4];
    int sB = lane + 64;
    #pragma unroll
    for (int p = 0; p < 4; p++) {
        erA[p] = actp[p] ? erp[p][lane] : 0.f;
        erB[p] = (actp[p] && sB < NPG) ? erp[p][sB] : 0.f;
    }
    #pragma unroll
    for (int p = 0; p < 4; p++) {
        int row = (wave * 4 + p) * PADW;
        if (actp[p]) {
            float add = ads[part * DPB + wave * 4 + p];
            float a1 = ass[lane] + add + erA[p];
            a1 = (a1 > 0.f) ? a1 : 0.2f * a1;
            coef[row + lane] = __expf(a1);
            if (sB < PADW) {
                float e2 = 0.f;
                if (sB < NPG) {
                    float a2 = ass[sB] + add + erB[p];
                    a2 = (a2 > 0.f) ? a2 : 0.2f * a2;
                    e2 = __expf(a2);
                }
                coef[row + sB] = e2;
            }
        } else {   // keep inactive rows finite-zero (stale LDS safety)
            coef[row + lane] = 0.f;
            if (sB < PADW) coef[row + sB] = 0.f;
        }
    }
    // per-wave coef: same-wave LDS write->read is ordered; no barrier needed

    // ---- aggregation + denominator ----
    int sbase = (lane >> 5) * 56;          // half 0: s 0..55, half 1: 56..111
    const float* c0p = &coef[(wave * 4 + 0) * PADW];
    const float* c1p = &coef[(wave * 4 + 1) * PADW];
    const float* c2p = &coef[(wave * 4 + 2) * PADW];
    const float* c3p = &coef[(wave * 4 + 3) * PADW];
    float acc0 = 0.f, acc1 = 0.f, acc2 = 0.f, acc3 = 0.f;
    float den0 = 0.f, den1 = 0.f, den2 = 0.f, den3 = 0.f;
    #pragma unroll
    for (int j4 = 0; j4 < 56; j4 += 4) {
        int s4 = sbase + j4;
        float4 hv = *(const float4*)&hs_t[c * TSTR + s4];
        float4 q0 = *(const float4*)&c0p[s4];
        float4 q1 = *(const float4*)&c1p[s4];
        float4 q2 = *(const float4*)&c2p[s4];
        float4 q3 = *(const float4*)&c3p[s4];
        acc0 += q0.x * hv.x + q0.y * hv.y + q0.z * hv.z + q0.w * hv.w;
        acc1 += q1.x * hv.x + q1.y * hv.y + q1.z * hv.z + q1.w * hv.w;
        acc2 += q2.x * hv.x + q2.y * hv.y + q2.z * hv.z + q2.w * hv.w;
        acc3 += q3.x * hv.x + q3.y * hv.y + q3.z * hv.z + q3.w * hv.w;
        den0 += (q0.x + q0.y) + (q0.z + q0.w);
        den1 += (q1.x + q1.y) + (q1.z + q1.w);
        den2 += (q2.x + q2.y) + (q2.z + q2.w);
        den3 += (q3.x + q3.y) + (q3.z + q3.w);
    }
    acc0 += __shfl_xor(acc0, 32);  den0 += __shfl_xor(den0, 32);
    acc1 += __shfl_xor(acc1, 32);  den1 += __shfl_xor(den1, 32);
    acc2 += __shfl_xor(acc2, 32);  den2 += __shfl_xor(den2, 32);
    acc3 += __shfl_xor(acc3, 32);  den3 += __shfl_xor(den3, 32);
    if (lane < 32) {
        float bv = bias[lane];
        size_t dbase = (size_t)g * NPG + part * DPB + wave * 4;
        if (actp[0]) h_out[(dbase + 0) * 32 + lane] = acc0 / den0 + bv;
        if (actp[1]) h_out[(dbase + 1) * 32 + lane] = acc1 / den1 + bv;
        if (actp[2]) h_out[(dbase + 2) * 32 + lane] = acc2 / den2 + bv;
        if (actp[3]) h_out[(dbase + 3) * 32 + lane] = acc3 / den3 + bv;
    }
}

// ---------------------------------------------------------------------------
// Kernel 3: global_add_pool + final linear + relu. grid = BGR blocks of 256.
__global__ void pool_kernel(const float* __restrict__ h2,
                            const float* __restrict__ linW,
                            const float* __restrict__ linb,
                            float* __restrict__ out) {
    int g = blockIdx.x;
    int t = threadIdx.x;
    int c = t & 31, r = t >> 5;
    const float* hg = h2 + (size_t)g * NPG * 32;
    float acc = 0.f;
    for (int i = r; i < NPG; i += 8) acc += hg[i * 32 + c];
    __shared__ float red[8][33];
    red[r][c] = acc;
    __syncthreads();
    if (t < 32) {
        float p = 0.f;
        #pragma unroll
        for (int rr = 0; rr < 8; rr++) p += red[rr][t];
        p *= linW[t];
        for (int off = 1; off < 32; off <<= 1) p += __shfl_xor(p, off);
        if (t == 0) out[g] = fmaxf(p + linb[0], 0.f);
    }
}

// ---------------------------------------------------------------------------
extern "C" void kernel_launch(void* const* d_in, const int* in_sizes, int n_in,
                              void* d_out, int out_size, void* d_ws, size_t ws_size,
                              hipStream_t stream) {
    // input order: x, edge_index, edge_attr, {W,as,ad,We,ae,b} x3, lin_W, lin_b
    const float* x    = (const float*)d_in[0];
    const float* ea   = (const float*)d_in[2];
    const float* W[3]  = {(const float*)d_in[3],  (const float*)d_in[9],  (const float*)d_in[15]};
    const float* as_[3]= {(const float*)d_in[4],  (const float*)d_in[10], (const float*)d_in[16]};
    const float* ad_[3]= {(const float*)d_in[5],  (const float*)d_in[11], (const float*)d_in[17]};
    const float* We[3] = {(const float*)d_in[6],  (const float*)d_in[12], (const float*)d_in[18]};
    const float* ae[3] = {(const float*)d_in[7],  (const float*)d_in[13], (const float*)d_in[19]};
    const float* b[3]  = {(const float*)d_in[8],  (const float*)d_in[14], (const float*)d_in[20]};
    const float* linW  = (const float*)d_in[21];
    const float* linb  = (const float*)d_in[22];
    float* out = (float*)d_out;

    float* ws   = (float*)d_ws;
    float* eatt = ws;                                     // 3*BGR*NPG*PADW
    float* h0   = eatt + (size_t)3 * BGR * NPG * PADW;    // NTOT*32
    float* h1   = h0   + (size_t)NTOT * 32;               // NTOT*32

    eatt_kernel<<<3 * BGR, 256, 0, stream>>>(ea, We[0], ae[0], We[1], ae[1],
                                             We[2], ae[2], eatt);

    gat_fused<<<BGR * 8, 256, 0, stream>>>(x, 1, 0, W[0], as_[0], ad_[0],
                                           eatt + (size_t)0 * BGR * NPG * PADW,
                                           b[0], h0);
    gat_fused<<<BGR * 8, 256, 0, stream>>>(h0, 0, 0, W[1], as_[1], ad_[1],
                                           eatt + (size_t)1 * BGR * NPG * PADW,
                                           b[1], h1);
    gat_fused<<<BGR * 8, 256, 0, stream>>>(h1, 0, 1, W[2], as_[2], ad_[2],
                                           eatt + (size_t)2 * BGR * NPG * PADW,
                                           b[2], h0);

    pool_kernel<<<BGR, 256, 0, stream>>>(h0, linW, linb, out);
}